// Round 1
// baseline (3489.336 us; speedup 1.0000x reference)
//
#include <hip/hip_runtime.h>
#include <hip/hip_bf16.h>

#define HH 512
#define WW 512
#define NB 8
#define IMG (HH*WW)
#define TS 15
#define NTL 35   // ceil(511/15)+1 tiles cover rows 0..524

// ---------- bf16 helpers (bit-exact RNE pack/unpack) ----------
__device__ __forceinline__ float bflo(unsigned u){ return __uint_as_float(u << 16); }
__device__ __forceinline__ float bfhi(unsigned u){ return __uint_as_float(u & 0xffff0000u); }
__device__ __forceinline__ unsigned f2bf_bits(float f){
    union { float f; unsigned u; } v; v.f = f;
    return (v.u + 0x7fffu + ((v.u >> 16) & 1u)) >> 16;   // RNE, finite inputs only
}
__device__ __forceinline__ unsigned packbf(float lo, float hi){
    return f2bf_bits(lo) | (f2bf_bits(hi) << 16);
}

// ---------- w2 [oc][ic][ky][kx] -> w2tT [tap][ic][oc] ----------
__global__ void prep_w2t_kernel(const float* __restrict__ w2, float* __restrict__ w2t)
{
    int i = blockIdx.x * 256 + threadIdx.x;
    if (i >= 9*64*64) return;
    int tap = i >> 12;          // /4096
    int rr  = i & 4095;
    int ic  = rr >> 6;
    int oc  = rr & 63;
    w2t[i] = w2[(oc*64 + ic)*9 + tap];
}

// ---------- erode(3x3 ones, zero pad, >1) then cur0 = 1 - known ----------
__global__ void erode_init_kernel(const float* __restrict__ mask, float* __restrict__ cur)
{
    int idx = blockIdx.x * 256 + threadIdx.x;         // 2M threads
    int b = idx >> 18, r = idx & (IMG - 1);
    int h = r >> 9, w = r & 511;
    const float* mb = mask + b*IMG;
    float s = 0.f;
    #pragma unroll
    for (int dy = -1; dy <= 1; ++dy){
        int hh = h + dy;
        if (hh < 0 || hh >= HH) continue;
        #pragma unroll
        for (int dx = -1; dx <= 1; ++dx){
            int ww = w + dx;
            if (ww < 0 || ww >= WW) continue;
            s += mb[hh*WW + ww];
        }
    }
    cur[idx] = (s > 1.0f) ? 0.f : 1.f;
}

// ---------- fused normalize + conv1 + conv2 + similarity maps ----------
// Tile: 15x15 sims output; feats 16x16; f 18x18 (halo 1); x 20x20 (halo 2).
// LDS: xs 4.8 KB + fs(18*18 px *128B, chunk-swizzled) 41.5 KB + ft(16*16 px) 32.8 KB = 79 KB -> 2 blocks/CU.
__global__ __launch_bounds__(256, 2)
void conv_sims_kernel(const float* __restrict__ img,
                      const float* __restrict__ w1, const float* __restrict__ b1,
                      const float* __restrict__ w2t, const float* __restrict__ b2,
                      float* __restrict__ vs, float* __restrict__ hs)
{
    __shared__ float xs[3][20][20];
    __shared__ uint4 fs4[18*18*8];     // per pixel: 64 bf16 = 8 uint4 chunks, chunk c stored at c^(pix&7)
    __shared__ uint4 ft4[16*16*8];

    const int tid = threadIdx.x;
    const int bid = blockIdx.x;
    const int b   = bid / (NTL*NTL);
    const int t2  = bid % (NTL*NTL);
    const int th  = t2 / NTL, tw = t2 % NTL;
    const int h0  = th * TS, w0 = tw * TS;

    // ---- phase 1: stage normalized input (zero pad outside image) ----
    for (int i = tid; i < 3*20*20; i += 256){
        int ic = i / 400, r = (i / 20) % 20, c = i % 20;
        int gy = h0 - 2 + r, gx = w0 - 2 + c;
        float mean = (ic == 0) ? 0.485f : (ic == 1) ? 0.456f : 0.406f;
        float istd = (ic == 0) ? (1.f/0.229f) : (ic == 1) ? (1.f/0.224f) : (1.f/0.225f);
        float v = 0.f;
        if (gy >= 0 && gy < HH && gx >= 0 && gx < WW)
            v = (img[(b*3 + ic)*IMG + gy*WW + gx] - mean) * istd;
        xs[ic][r][c] = v;
    }
    __syncthreads();

    // ---- phase 2: conv1 (3->64) + relu -> fs (bf16, swizzled). fs=0 outside image (zero pad for conv2). ----
    for (int p = tid; p < 18*18; p += 256){
        int fy = p / 18, fx = p % 18;
        int gy = h0 - 1 + fy, gx = w0 - 1 + fx;
        bool inimg = (gy >= 0 && gy < HH && gx >= 0 && gx < WW);
        float xv[27];
        #pragma unroll
        for (int ic = 0; ic < 3; ++ic)
            #pragma unroll
            for (int ky = 0; ky < 3; ++ky)
                #pragma unroll
                for (int kx = 0; kx < 3; ++kx)
                    xv[ic*9 + ky*3 + kx] = xs[ic][fy + ky][fx + kx];
        int sw = p & 7;
        for (int g = 0; g < 8; ++g){               // 8 oc per pass
            float a[8];
            #pragma unroll
            for (int j = 0; j < 8; ++j){
                int oc = g*8 + j;
                const float* wp = w1 + oc*27;      // uniform -> scalar loads
                float acc = b1[oc];
                #pragma unroll
                for (int q = 0; q < 27; ++q) acc = fmaf(wp[q], xv[q], acc);
                a[j] = inimg ? fmaxf(acc, 0.f) : 0.f;
            }
            uint4 vq;
            vq.x = packbf(a[0], a[1]); vq.y = packbf(a[2], a[3]);
            vq.z = packbf(a[4], a[5]); vq.w = packbf(a[6], a[7]);
            fs4[p*8 + (g ^ sw)] = vq;
        }
    }
    __syncthreads();

    // ---- phase 3: conv2 (64->64) + relu -> ft. One pixel per thread, acc[64] static-indexed. ----
    {
        const int y = tid >> 4, x = tid & 15;
        float acc[64];
        #pragma unroll
        for (int oc = 0; oc < 64; ++oc) acc[oc] = b2[oc];

        const unsigned* fsw = (const unsigned*)fs4;
        for (int tap = 0; tap < 9; ++tap){
            int dy = tap / 3, dx = tap % 3;
            int pix = (y + dy)*18 + (x + dx);
            int pbase = pix * 32;                  // 32 dwords per pixel
            int swz = (pix & 7) << 2;              // chunk swizzle in dword units
            const float* wtap = w2t + tap*4096;    // [ic][oc]
            #pragma unroll 1
            for (int kk = 0; kk < 32; ++kk){       // 2 input channels per iter
                int dws = ((kk & ~3) ^ swz) | (kk & 3);
                unsigned u = fsw[pbase + dws];
                float fa = bflo(u), fb = bfhi(u);
                const float* wr0 = wtap + (2*kk    )*64;   // uniform -> scalar loads
                const float* wr1 = wtap + (2*kk + 1)*64;
                #pragma unroll
                for (int oc = 0; oc < 64; ++oc)
                    acc[oc] = fmaf(wr1[oc], fb, fmaf(wr0[oc], fa, acc[oc]));
            }
        }
        int sw2 = tid & 7;
        #pragma unroll
        for (int g = 0; g < 8; ++g){
            float a0 = fmaxf(acc[g*8+0], 0.f), a1 = fmaxf(acc[g*8+1], 0.f);
            float a2 = fmaxf(acc[g*8+2], 0.f), a3 = fmaxf(acc[g*8+3], 0.f);
            float a4 = fmaxf(acc[g*8+4], 0.f), a5 = fmaxf(acc[g*8+5], 0.f);
            float a6 = fmaxf(acc[g*8+6], 0.f), a7 = fmaxf(acc[g*8+7], 0.f);
            uint4 vq;
            vq.x = packbf(a0, a1); vq.y = packbf(a2, a3);
            vq.z = packbf(a4, a5); vq.w = packbf(a6, a7);
            ft4[tid*8 + (g ^ sw2)] = vq;
        }
    }
    __syncthreads();

    // ---- phase 4: similarity maps. vsim/hsim full coverage incl. zero rows/cols at 511. ----
    for (int s = tid; s < 450; s += 256){
        bool isv = (s < 225);
        int r  = isv ? s : (s - 225);
        int sy = r / 15, sx = r % 15;
        int gh = h0 + sy, gw = w0 + sx;
        if (gh >= HH || gw >= WW) continue;
        int pa = sy*16 + sx;
        int pb = isv ? (pa + 16) : (pa + 1);
        const uint4* A = ft4 + pa*8; int sa = pa & 7;
        const uint4* B = ft4 + pb*8; int sb = pb & 7;
        float ssd = 0.f;
        #pragma unroll
        for (int j = 0; j < 8; ++j){
            uint4 qa = A[j ^ sa], qb = B[j ^ sb];
            unsigned da[4] = {qa.x, qa.y, qa.z, qa.w};
            unsigned db[4] = {qb.x, qb.y, qb.z, qb.w};
            #pragma unroll
            for (int k = 0; k < 4; ++k){
                float d0 = bflo(da[k]) - bflo(db[k]);
                float d1 = bfhi(da[k]) - bfhi(db[k]);
                ssd = fmaf(d0, d0, ssd);
                ssd = fmaf(d1, d1, ssd);
            }
        }
        float sim = __expf(ssd * (-1.f/500.f));
        int o = b*IMG + gh*WW + gw;
        if (isv) vs[o] = (gh < HH-1) ? sim : 0.f;   // row 511 = 0
        else     hs[o] = (gw < WW-1) ? sim : 0.f;   // col 511 = 0
    }
}

// ---------- one Jacobi propagation step; FINAL fuses min(mask, 1-cur) -> d_out ----------
template<bool FINAL>
__global__ void prop_kernel(const float* __restrict__ cin, float* __restrict__ cout,
                            const float* __restrict__ vs, const float* __restrict__ hs,
                            const float* __restrict__ mask, float* __restrict__ dout)
{
    int idx = blockIdx.x * 256 + threadIdx.x;
    int b = idx >> 18, r = idx & (IMG - 1);
    int h = r >> 9, w = r & 511;
    int base = b * IMG;
    int hm = (h > 0)   ? h - 1 : 0;
    int hp = (h < 511) ? h + 1 : 511;
    int wm = (w > 0)   ? w - 1 : 0;
    int wp = (w < 511) ? w + 1 : 511;
    float c  = cin[base + h*WW + w];
    float tp = cin[base + hm*WW + w ] * vs[base + hm*WW + w];
    float bt = cin[base + hp*WW + w ] * vs[base + h *WW + w];
    float lf = cin[base + h *WW + wm] * hs[base + h *WW + wm];
    float rg = cin[base + h *WW + wp] * hs[base + h *WW + w ];
    float res = fmaxf(fmaxf(c, fmaxf(tp, bt)), fmaxf(lf, rg));
    if (FINAL) dout[idx] = fminf(mask[idx], 1.f - res);
    else       cout[idx] = res;
}

extern "C" void kernel_launch(void* const* d_in, const int* in_sizes, int n_in,
                              void* d_out, int out_size, void* d_ws, size_t ws_size,
                              hipStream_t stream)
{
    const float* img  = (const float*)d_in[0];
    // d_in[1] (pred_img) is unused by the reference.
    const float* mask = (const float*)d_in[2];
    const float* w1   = (const float*)d_in[3];
    const float* b1   = (const float*)d_in[4];
    const float* w2   = (const float*)d_in[5];
    const float* b2   = (const float*)d_in[6];
    float* out = (float*)d_out;

    float* vs   = (float*)d_ws;            // [8][512][512]
    float* hsm  = vs   + NB*IMG;           // [8][512][512]
    float* curA = hsm  + NB*IMG;
    float* curB = curA + NB*IMG;
    float* w2t  = curB + NB*IMG;           // [9][64][64]

    prep_w2t_kernel<<<144, 256, 0, stream>>>(w2, w2t);
    erode_init_kernel<<<NB*IMG/256, 256, 0, stream>>>(mask, curA);
    conv_sims_kernel<<<NB*NTL*NTL, 256, 0, stream>>>(img, w1, b1, w2t, b2, vs, hsm);

    float* pin = curA;
    float* pout = curB;
    for (int it = 0; it < 9; ++it){
        prop_kernel<false><<<NB*IMG/256, 256, 0, stream>>>(pin, pout, vs, hsm, mask, out);
        float* t = pin; pin = pout; pout = t;
    }
    prop_kernel<true><<<NB*IMG/256, 256, 0, stream>>>(pin, pout, vs, hsm, mask, out);
}

// Round 3
// 733.279 us; speedup vs baseline: 4.7585x; 4.7585x over previous
//
#include <hip/hip_runtime.h>
#include <hip/hip_bf16.h>

#define HH 512
#define WW 512
#define NB 8
#define IMG (HH*WW)
#define TS 15
#define NTL 35   // ceil(511/15)+1 tiles cover rows 0..524

typedef __bf16 bf16x8 __attribute__((ext_vector_type(8)));
typedef float  f32x4  __attribute__((ext_vector_type(4)));

// ---------- bf16 helpers (RNE pack/unpack) ----------
__device__ __forceinline__ float bflo(unsigned u){ return __uint_as_float(u << 16); }
__device__ __forceinline__ float bfhi(unsigned u){ return __uint_as_float(u & 0xffff0000u); }
__device__ __forceinline__ unsigned f2bf_bits(float f){
    union { float f; unsigned u; } v; v.f = f;
    return (v.u + 0x7fffu + ((v.u >> 16) & 1u)) >> 16;   // RNE, finite inputs only
}
__device__ __forceinline__ unsigned packbf(float lo, float hi){
    return f2bf_bits(lo) | (f2bf_bits(hi) << 16);
}

// ---------- w2 [oc][ic][tap] -> B-fragment layout [tap][ks][nf][lane] of 8 bf16 ----------
// lane l, elem j: ic = ks*32 + (l>>4)*8 + j, oc = nf*16 + (l&15)
__global__ void prep_wb_kernel(const float* __restrict__ w2, uint4* __restrict__ wb)
{
    int i = blockIdx.x * 256 + threadIdx.x;
    if (i >= 9*2*4*64) return;
    int tap = i >> 9;
    int rem = i & 511;
    int ks  = rem >> 8;
    int nf  = (rem >> 6) & 3;
    int l   = rem & 63;
    int oc  = nf*16 + (l & 15);
    int icb = ks*32 + (l >> 4)*8;
    float v[8];
    #pragma unroll
    for (int j = 0; j < 8; ++j)
        v[j] = w2[(oc*64 + icb + j)*9 + tap];
    uint4 q;
    q.x = packbf(v[0], v[1]); q.y = packbf(v[2], v[3]);
    q.z = packbf(v[4], v[5]); q.w = packbf(v[6], v[7]);
    wb[i] = q;
}

// ---------- erode(3x3 ones, zero pad, >1) then cur0 = 1 - known ----------
__global__ void erode_init_kernel(const float* __restrict__ mask, float* __restrict__ cur)
{
    int idx = blockIdx.x * 256 + threadIdx.x;
    int b = idx >> 18, r = idx & (IMG - 1);
    int h = r >> 9, w = r & 511;
    const float* mb = mask + b*IMG;
    float s = 0.f;
    #pragma unroll
    for (int dy = -1; dy <= 1; ++dy){
        int hh = h + dy;
        if (hh < 0 || hh >= HH) continue;
        #pragma unroll
        for (int dx = -1; dx <= 1; ++dx){
            int ww = w + dx;
            if (ww < 0 || ww >= WW) continue;
            s += mb[hh*WW + ww];
        }
    }
    cur[idx] = (s > 1.0f) ? 0.f : 1.f;
}

// ---------- fused normalize + conv1(VALU) + conv2(MFMA) + similarity maps ----------
// Tile: 15x15 sims; conv2 out 16x16 (256 px); F 18x18 (halo 1); x 20x20 (halo 2).
// LDS 79 KB -> 2 blocks/CU. F tile chunk-XOR swizzled (slot = chunk ^ (px&7)).
__global__ __launch_bounds__(256, 2)
void conv_sims_kernel(const float* __restrict__ img,
                      const float* __restrict__ w1, const float* __restrict__ b1,
                      const uint4* __restrict__ wb, const float* __restrict__ b2,
                      float* __restrict__ vs, float* __restrict__ hs)
{
    __shared__ float xs[3][20][20];
    __shared__ uint4 fs4[18*18*8];
    __shared__ uint4 ft4[16*16*8];

    const int tid = threadIdx.x;
    const int bid = blockIdx.x;
    const int b   = bid / (NTL*NTL);
    const int t2  = bid % (NTL*NTL);
    const int th  = t2 / NTL, tw = t2 % NTL;
    const int h0  = th * TS, w0 = tw * TS;

    // ---- phase 1: stage normalized input (zero outside image) ----
    for (int i = tid; i < 3*20*20; i += 256){
        int ic = i / 400, r = (i / 20) % 20, c = i % 20;
        int gy = h0 - 2 + r, gx = w0 - 2 + c;
        float mean = (ic == 0) ? 0.485f : (ic == 1) ? 0.456f : 0.406f;
        float istd = (ic == 0) ? (1.f/0.229f) : (ic == 1) ? (1.f/0.224f) : (1.f/0.225f);
        float v = 0.f;
        if (gy >= 0 && gy < HH && gx >= 0 && gx < WW)
            v = (img[(b*3 + ic)*IMG + gy*WW + gx] - mean) * istd;
        xs[ic][r][c] = v;
    }
    __syncthreads();

    // ---- phase 2: conv1 (3->64) + relu -> fs (bf16, swizzled); zero outside image ----
    for (int p = tid; p < 18*18; p += 256){
        int fy = p / 18, fx = p % 18;
        int gy = h0 - 1 + fy, gx = w0 - 1 + fx;
        bool inimg = (gy >= 0 && gy < HH && gx >= 0 && gx < WW);
        float xv[27];
        #pragma unroll
        for (int ic = 0; ic < 3; ++ic)
            #pragma unroll
            for (int ky = 0; ky < 3; ++ky)
                #pragma unroll
                for (int kx = 0; kx < 3; ++kx)
                    xv[ic*9 + ky*3 + kx] = xs[ic][fy + ky][fx + kx];
        int sw = p & 7;
        for (int g = 0; g < 8; ++g){
            float a[8];
            #pragma unroll
            for (int j = 0; j < 8; ++j){
                int oc = g*8 + j;
                const float* wp = w1 + oc*27;      // wave-uniform -> scalar loads
                float acc = b1[oc];
                #pragma unroll
                for (int q = 0; q < 27; ++q) acc = fmaf(wp[q], xv[q], acc);
                a[j] = inimg ? fmaxf(acc, 0.f) : 0.f;
            }
            uint4 vq;
            vq.x = packbf(a[0], a[1]); vq.y = packbf(a[2], a[3]);
            vq.z = packbf(a[4], a[5]); vq.w = packbf(a[6], a[7]);
            fs4[p*8 + (g ^ sw)] = vq;
        }
    }
    __syncthreads();

    // ---- phase 3: conv2 (64->64) via MFMA 16x16x32 bf16, 4 waves x (64 px, 64 oc) ----
    {
        const int wv = tid >> 6;         // wave id: pixels [64*wv, 64*wv+64)
        const int l  = tid & 63;
        const int lr = l & 15;           // A row / B col / D col
        const int kg = l >> 4;           // k-group

        f32x4 acc[4][4];
        #pragma unroll
        for (int nf = 0; nf < 4; ++nf){
            float bv = b2[nf*16 + lr];
            #pragma unroll
            for (int mf = 0; mf < 4; ++mf)
                acc[mf][nf] = (f32x4){bv, bv, bv, bv};
        }

        const bf16x8* fsb = (const bf16x8*)fs4;
        const bf16x8* wbv = (const bf16x8*)wb;

        #pragma unroll 1
        for (int tap = 0; tap < 9; ++tap){
            const int dy = tap / 3, dx = tap % 3;
            bf16x8 bfr[2][4];
            #pragma unroll
            for (int ks = 0; ks < 2; ++ks)
                #pragma unroll
                for (int nf = 0; nf < 4; ++nf)
                    bfr[ks][nf] = wbv[((tap*8 + ks*4 + nf) << 6) + l];
            #pragma unroll
            for (int ks = 0; ks < 2; ++ks){
                #pragma unroll
                for (int mf = 0; mf < 4; ++mf){
                    // pixel p = 64*wv + mf*16 + lr: ty = 4*wv+mf (const/lane), tx = lr
                    int fpx = (wv*4 + mf + dy)*18 + lr + dx;
                    bf16x8 af = fsb[fpx*8 + ((ks*4 + kg) ^ (fpx & 7))];
                    #pragma unroll
                    for (int nf = 0; nf < 4; ++nf)
                        acc[mf][nf] = __builtin_amdgcn_mfma_f32_16x16x32_bf16(
                            af, bfr[ks][nf], acc[mf][nf], 0, 0, 0);
                }
            }
        }

        // write ft (relu, bf16, swizzled). D: row = 4*kg + r, col = lr.
        unsigned short* ftu = (unsigned short*)ft4;
        #pragma unroll
        for (int mf = 0; mf < 4; ++mf)
            #pragma unroll
            for (int nf = 0; nf < 4; ++nf)
                #pragma unroll
                for (int r = 0; r < 4; ++r){
                    int p  = wv*64 + mf*16 + kg*4 + r;
                    int oc = nf*16 + lr;
                    float v = fmaxf(acc[mf][nf][r], 0.f);
                    ftu[p*64 + (((oc >> 3) ^ (p & 7)) << 3) + (oc & 7)] =
                        (unsigned short)f2bf_bits(v);
                }
    }
    __syncthreads();

    // ---- phase 4: similarity maps (full coverage incl. zero row/col 511) ----
    for (int s = tid; s < 450; s += 256){
        bool isv = (s < 225);
        int r  = isv ? s : (s - 225);
        int sy = r / 15, sx = r % 15;
        int gh = h0 + sy, gw = w0 + sx;
        if (gh >= HH || gw >= WW) continue;
        int pa = sy*16 + sx;
        int pb = isv ? (pa + 16) : (pa + 1);
        const uint4* A = ft4 + pa*8; int sa = pa & 7;
        const uint4* B = ft4 + pb*8; int sb = pb & 7;
        float ssd = 0.f;
        #pragma unroll
        for (int j = 0; j < 8; ++j){
            uint4 qa = A[j ^ sa], qb = B[j ^ sb];
            unsigned da[4] = {qa.x, qa.y, qa.z, qa.w};
            unsigned db[4] = {qb.x, qb.y, qb.z, qb.w};
            #pragma unroll
            for (int k = 0; k < 4; ++k){
                float d0 = bflo(da[k]) - bflo(db[k]);
                float d1 = bfhi(da[k]) - bfhi(db[k]);
                ssd = fmaf(d0, d0, ssd);
                ssd = fmaf(d1, d1, ssd);
            }
        }
        float sim = __expf(ssd * (-1.f/500.f));
        int o = b*IMG + gh*WW + gw;
        if (isv) vs[o] = (gh < HH-1) ? sim : 0.f;
        else     hs[o] = (gw < WW-1) ? sim : 0.f;
    }
}

// ---------- one Jacobi propagation step; FINAL fuses min(mask, 1-cur) -> d_out ----------
template<bool FINAL>
__global__ void prop_kernel(const float* __restrict__ cin, float* __restrict__ cout,
                            const float* __restrict__ vs, const float* __restrict__ hs,
                            const float* __restrict__ mask, float* __restrict__ dout)
{
    int idx = blockIdx.x * 256 + threadIdx.x;
    int b = idx >> 18, r = idx & (IMG - 1);
    int h = r >> 9, w = r & 511;
    int base = b * IMG;
    int hm = (h > 0)   ? h - 1 : 0;
    int hp = (h < 511) ? h + 1 : 511;
    int wm = (w > 0)   ? w - 1 : 0;
    int wp = (w < 511) ? w + 1 : 511;
    float c  = cin[base + h*WW + w];
    float tp = cin[base + hm*WW + w ] * vs[base + hm*WW + w];
    float bt = cin[base + hp*WW + w ] * vs[base + h *WW + w];
    float lf = cin[base + h *WW + wm] * hs[base + h *WW + wm];
    float rg = cin[base + h *WW + wp] * hs[base + h *WW + w ];
    float res = fmaxf(fmaxf(c, fmaxf(tp, bt)), fmaxf(lf, rg));
    if (FINAL) dout[idx] = fminf(mask[idx], 1.f - res);
    else       cout[idx] = res;
}

extern "C" void kernel_launch(void* const* d_in, const int* in_sizes, int n_in,
                              void* d_out, int out_size, void* d_ws, size_t ws_size,
                              hipStream_t stream)
{
    const float* img  = (const float*)d_in[0];
    // d_in[1] (pred_img) unused by the reference.
    const float* mask = (const float*)d_in[2];
    const float* w1   = (const float*)d_in[3];
    const float* b1   = (const float*)d_in[4];
    const float* w2   = (const float*)d_in[5];
    const float* b2   = (const float*)d_in[6];
    float* out = (float*)d_out;

    float* vs   = (float*)d_ws;            // [8][512][512]
    float* hsm  = vs   + NB*IMG;
    float* curA = hsm  + NB*IMG;
    float* curB = curA + NB*IMG;
    uint4* wbuf = (uint4*)(curB + NB*IMG); // [9*2*4*64] B-fragments

    prep_wb_kernel<<<18, 256, 0, stream>>>(w2, wbuf);
    erode_init_kernel<<<NB*IMG/256, 256, 0, stream>>>(mask, curA);
    conv_sims_kernel<<<NB*NTL*NTL, 256, 0, stream>>>(img, w1, b1, wbuf, b2, vs, hsm);

    float* pin = curA;
    float* pout = curB;
    for (int it = 0; it < 9; ++it){
        prop_kernel<false><<<NB*IMG/256, 256, 0, stream>>>(pin, pout, vs, hsm, mask, out);
        float* t = pin; pin = pout; pout = t;
    }
    prop_kernel<true><<<NB*IMG/256, 256, 0, stream>>>(pin, pout, vs, hsm, mask, out);
}

// Round 4
// 456.795 us; speedup vs baseline: 7.6387x; 1.6053x over previous
//
#include <hip/hip_runtime.h>
#include <hip/hip_bf16.h>

#define HH 512
#define WW 512
#define NB 8
#define IMG (HH*WW)
#define TS 15
#define NTL 35   // ceil(511/15)+1 tiles cover rows 0..524

typedef __bf16 bf16x8 __attribute__((ext_vector_type(8)));
typedef float  f32x4  __attribute__((ext_vector_type(4)));

// ---------- bf16 helpers (RNE pack/unpack) ----------
__device__ __forceinline__ float bflo(unsigned u){ return __uint_as_float(u << 16); }
__device__ __forceinline__ float bfhi(unsigned u){ return __uint_as_float(u & 0xffff0000u); }
__device__ __forceinline__ unsigned f2bf_bits(float f){
    union { float f; unsigned u; } v; v.f = f;
    return (v.u + 0x7fffu + ((v.u >> 16) & 1u)) >> 16;   // RNE, finite inputs only
}
__device__ __forceinline__ unsigned packbf(float lo, float hi){
    return f2bf_bits(lo) | (f2bf_bits(hi) << 16);
}

// ---------- weight prep ----------
// wb: w2 [oc][ic][tap] -> B-frag [tap][ks][nf][lane]: ic = ks*32+(l>>4)*8+j, oc = nf*16+(l&15)
// wa: w1 [oc][k=27]    -> A-frag [mf][lane]:          oc = mf*16+(l&15),  k = (l>>4)*8+j (k>=27 -> 0)
__global__ void prep_kernel(const float* __restrict__ w2, const float* __restrict__ w1,
                            uint4* __restrict__ wb, uint4* __restrict__ wa)
{
    int i = blockIdx.x * 256 + threadIdx.x;
    if (i < 9*2*4*64){
        int tap = i >> 9;
        int rem = i & 511;
        int ks  = rem >> 8;
        int nf  = (rem >> 6) & 3;
        int l   = rem & 63;
        int oc  = nf*16 + (l & 15);
        int icb = ks*32 + (l >> 4)*8;
        float v[8];
        #pragma unroll
        for (int j = 0; j < 8; ++j)
            v[j] = w2[(oc*64 + icb + j)*9 + tap];
        uint4 q;
        q.x = packbf(v[0], v[1]); q.y = packbf(v[2], v[3]);
        q.z = packbf(v[4], v[5]); q.w = packbf(v[6], v[7]);
        wb[i] = q;
    } else if (i < 9*2*4*64 + 4*64){
        int idx = i - 9*2*4*64;
        int mf = idx >> 6, l = idx & 63;
        int oc = mf*16 + (l & 15);
        int kb = (l >> 4)*8;
        float v[8];
        #pragma unroll
        for (int j = 0; j < 8; ++j)
            v[j] = (kb + j < 27) ? w1[oc*27 + kb + j] : 0.f;
        uint4 q;
        q.x = packbf(v[0], v[1]); q.y = packbf(v[2], v[3]);
        q.z = packbf(v[4], v[5]); q.w = packbf(v[6], v[7]);
        wa[idx] = q;
    }
}

// ---------- erode(3x3 ones, zero pad, >1) then cur0 = 1 - known ----------
__global__ void erode_init_kernel(const float* __restrict__ mask, float* __restrict__ cur)
{
    int idx = blockIdx.x * 256 + threadIdx.x;
    int b = idx >> 18, r = idx & (IMG - 1);
    int h = r >> 9, w = r & 511;
    const float* mb = mask + b*IMG;
    float s = 0.f;
    #pragma unroll
    for (int dy = -1; dy <= 1; ++dy){
        int hh = h + dy;
        if (hh < 0 || hh >= HH) continue;
        #pragma unroll
        for (int dx = -1; dx <= 1; ++dx){
            int ww = w + dx;
            if (ww < 0 || ww >= WW) continue;
            s += mb[hh*WW + ww];
        }
    }
    cur[idx] = (s > 1.0f) ? 0.f : 1.f;
}

// ---------- fused normalize + conv1(MFMA) + conv2(MFMA) + similarity maps ----------
// Tile: 15x15 sims; conv2 out 16x16; F 18x18 (halo 1); x 20x20 (halo 2).
// LDS: xs 4.8K + fs4 41.5K + union{xi 21.5K, ft4 32.8K} = 79 KB -> 2 blocks/CU.
__global__ __launch_bounds__(256, 2)
void conv_sims_kernel(const float* __restrict__ img,
                      const float* __restrict__ b1,
                      const uint4* __restrict__ wa,
                      const uint4* __restrict__ wb, const float* __restrict__ b2,
                      float* __restrict__ vs, float* __restrict__ hs)
{
    __shared__ float xs[3][20][20];
    __shared__ uint4 fs4[324*8];
    __shared__ uint4 uni[2048];          // xi (conv1 B operand) then ft4 (conv2 out)

    const int tid = threadIdx.x;
    const int bid = blockIdx.x;
    const int b   = bid / (NTL*NTL);
    const int t2  = bid % (NTL*NTL);
    const int th  = t2 / NTL, tw = t2 % NTL;
    const int h0  = th * TS, w0 = tw * TS;

    // ---- phase 1: stage normalized input (zero outside image) ----
    for (int i = tid; i < 3*20*20; i += 256){
        int ic = i / 400, r = (i / 20) % 20, c = i % 20;
        int gy = h0 - 2 + r, gx = w0 - 2 + c;
        float mean = (ic == 0) ? 0.485f : (ic == 1) ? 0.456f : 0.406f;
        float istd = (ic == 0) ? (1.f/0.229f) : (ic == 1) ? (1.f/0.224f) : (1.f/0.225f);
        float v = 0.f;
        if (gy >= 0 && gy < HH && gx >= 0 && gx < WW)
            v = (img[(b*3 + ic)*IMG + gy*WW + gx] - mean) * istd;
        xs[ic][r][c] = v;
    }
    __syncthreads();

    // ---- phase 2a: build im2col records xi[336][32 bf16], chunk-swizzled slot = c^(p&3) ----
    {
        uint4* xi = uni;
        for (int p = tid; p < 336; p += 256){
            uint4 c0 = {0,0,0,0}, c1 = c0, c2 = c0, c3 = c0;
            if (p < 324){
                int fy = p / 18, fx = p % 18;
                float xv[27];
                #pragma unroll
                for (int ic = 0; ic < 3; ++ic)
                    #pragma unroll
                    for (int ky = 0; ky < 3; ++ky)
                        #pragma unroll
                        for (int kx = 0; kx < 3; ++kx)
                            xv[ic*9 + ky*3 + kx] = xs[ic][fy + ky][fx + kx];
                c0.x = packbf(xv[0], xv[1]);  c0.y = packbf(xv[2], xv[3]);
                c0.z = packbf(xv[4], xv[5]);  c0.w = packbf(xv[6], xv[7]);
                c1.x = packbf(xv[8], xv[9]);  c1.y = packbf(xv[10], xv[11]);
                c1.z = packbf(xv[12], xv[13]);c1.w = packbf(xv[14], xv[15]);
                c2.x = packbf(xv[16], xv[17]);c2.y = packbf(xv[18], xv[19]);
                c2.z = packbf(xv[20], xv[21]);c2.w = packbf(xv[22], xv[23]);
                c3.x = packbf(xv[24], xv[25]);c3.y = packbf(xv[26], 0.f);
            }
            int sw = p & 3;
            xi[p*4 + (0 ^ sw)] = c0;
            xi[p*4 + (1 ^ sw)] = c1;
            xi[p*4 + (2 ^ sw)] = c2;
            xi[p*4 + (3 ^ sw)] = c3;
        }
    }
    __syncthreads();

    // ---- phase 2b: conv1 via MFMA. D[row=oc][col=pixel]; K=32 in one step. ----
    {
        const int l  = tid & 63, wv = tid >> 6;
        const int lr = l & 15,  kg = l >> 4;
        const bf16x8* wav = (const bf16x8*)wa;
        const bf16x8* xib = (const bf16x8*)uni;

        bf16x8 af[4];
        #pragma unroll
        for (int mf = 0; mf < 4; ++mf) af[mf] = wav[(mf << 6) + l];
        f32x4 binit[4];
        #pragma unroll
        for (int mf = 0; mf < 4; ++mf)
            binit[mf] = *(const f32x4*)(b1 + mf*16 + kg*4);

        for (int nb = wv; nb < 21; nb += 4){
            int px = nb*16 + lr;
            bf16x8 bf = xib[px*4 + (kg ^ (px & 3))];
            int fy = px / 18, fx = px % 18;
            int gy = h0 - 1 + fy, gx = w0 - 1 + fx;
            bool inimg = (px < 324) && gy >= 0 && gy < HH && gx >= 0 && gx < WW;
            #pragma unroll
            for (int mf = 0; mf < 4; ++mf){
                f32x4 acc = __builtin_amdgcn_mfma_f32_16x16x32_bf16(af[mf], bf, binit[mf], 0, 0, 0);
                unsigned lo = 0, hi = 0;
                if (inimg){
                    lo = packbf(fmaxf(acc[0], 0.f), fmaxf(acc[1], 0.f));
                    hi = packbf(fmaxf(acc[2], 0.f), fmaxf(acc[3], 0.f));
                }
                if (px < 324){
                    char* p8 = (char*)fs4 + px*128 + (((mf*2 + (kg >> 1)) ^ (px & 7)) << 4) + ((kg & 1) << 3);
                    uint2 w2v; w2v.x = lo; w2v.y = hi;
                    *(uint2*)p8 = w2v;
                }
            }
        }
    }
    __syncthreads();

    // ---- phase 3: conv2 (64->64) via MFMA, 4 waves x (64 px, 64 oc) ----
    {
        const int wv = tid >> 6;
        const int l  = tid & 63;
        const int lr = l & 15;
        const int kg = l >> 4;

        f32x4 acc[4][4];
        #pragma unroll
        for (int nf = 0; nf < 4; ++nf){
            float bv = b2[nf*16 + lr];
            #pragma unroll
            for (int mf = 0; mf < 4; ++mf)
                acc[mf][nf] = (f32x4){bv, bv, bv, bv};
        }

        const bf16x8* fsb = (const bf16x8*)fs4;
        const bf16x8* wbv = (const bf16x8*)wb;

        #pragma unroll 1
        for (int tap = 0; tap < 9; ++tap){
            const int dy = tap / 3, dx = tap % 3;
            bf16x8 bfr[2][4];
            #pragma unroll
            for (int ks = 0; ks < 2; ++ks)
                #pragma unroll
                for (int nf = 0; nf < 4; ++nf)
                    bfr[ks][nf] = wbv[((tap*8 + ks*4 + nf) << 6) + l];
            #pragma unroll
            for (int ks = 0; ks < 2; ++ks){
                #pragma unroll
                for (int mf = 0; mf < 4; ++mf){
                    int fpx = (wv*4 + mf + dy)*18 + lr + dx;
                    bf16x8 afr = fsb[fpx*8 + ((ks*4 + kg) ^ (fpx & 7))];
                    #pragma unroll
                    for (int nf = 0; nf < 4; ++nf)
                        acc[mf][nf] = __builtin_amdgcn_mfma_f32_16x16x32_bf16(
                            afr, bfr[ks][nf], acc[mf][nf], 0, 0, 0);
                }
            }
        }

        // write ft (relu, bf16, swizzled). D: row = 4*kg + r, col = lr.
        unsigned short* ftu = (unsigned short*)uni;
        #pragma unroll
        for (int mf = 0; mf < 4; ++mf)
            #pragma unroll
            for (int nf = 0; nf < 4; ++nf)
                #pragma unroll
                for (int r = 0; r < 4; ++r){
                    int p  = wv*64 + mf*16 + kg*4 + r;
                    int oc = nf*16 + lr;
                    float v = fmaxf(acc[mf][nf][r], 0.f);
                    ftu[p*64 + (((oc >> 3) ^ (p & 7)) << 3) + (oc & 7)] =
                        (unsigned short)f2bf_bits(v);
                }
    }
    __syncthreads();

    // ---- phase 4: similarity maps (full coverage incl. zero row/col 511) ----
    const uint4* ft4 = uni;
    for (int s = tid; s < 450; s += 256){
        bool isv = (s < 225);
        int r  = isv ? s : (s - 225);
        int sy = r / 15, sx = r % 15;
        int gh = h0 + sy, gw = w0 + sx;
        if (gh >= HH || gw >= WW) continue;
        int pa = sy*16 + sx;
        int pb = isv ? (pa + 16) : (pa + 1);
        const uint4* A = ft4 + pa*8; int sa = pa & 7;
        const uint4* B = ft4 + pb*8; int sb = pb & 7;
        float ssd = 0.f;
        #pragma unroll
        for (int j = 0; j < 8; ++j){
            uint4 qa = A[j ^ sa], qb = B[j ^ sb];
            unsigned da[4] = {qa.x, qa.y, qa.z, qa.w};
            unsigned db[4] = {qb.x, qb.y, qb.z, qb.w};
            #pragma unroll
            for (int k = 0; k < 4; ++k){
                float d0 = bflo(da[k]) - bflo(db[k]);
                float d1 = bfhi(da[k]) - bfhi(db[k]);
                ssd = fmaf(d0, d0, ssd);
                ssd = fmaf(d1, d1, ssd);
            }
        }
        float sim = __expf(ssd * (-1.f/500.f));
        int o = b*IMG + gh*WW + gw;
        if (isv) vs[o] = (gh < HH-1) ? sim : 0.f;
        else     hs[o] = (gw < WW-1) ? sim : 0.f;
    }
}

// ---------- fused 5-iteration Jacobi propagation (64x64 tile + 5 halo in LDS) ----------
// Replicate-clamped staging reproduces the reference's clamped indexing exactly
// (all pad terms are cur*sim <= cur, dominated under max). FINAL fuses min(mask,1-cur).
template<bool FINAL>
__global__ __launch_bounds__(256, 2)
void prop5_kernel(const float* __restrict__ cin, float* __restrict__ cout,
                  const float* __restrict__ vs, const float* __restrict__ hs,
                  const float* __restrict__ mask, float* __restrict__ dout)
{
    __shared__ float cu[74*76];
    __shared__ float vl[74*76];
    __shared__ float hl[74*76];

    const int tid = threadIdx.x;
    const int bid = blockIdx.x;                 // 512 = b(8) x ty(8) x tx(8)
    const int b  = bid >> 6;
    const int ty = (bid >> 3) & 7, tx = bid & 7;
    const int gy0 = ty*64 - 5, gx0 = tx*64 - 5;
    const float* cb = cin + b*IMG;
    const float* vb = vs  + b*IMG;
    const float* hb = hs  + b*IMG;

    for (int i = tid; i < 74*74; i += 256){
        int ly = i / 74, lx = i % 74;
        int gy = min(max(gy0 + ly, 0), 511);
        int gx = min(max(gx0 + lx, 0), 511);
        int g = gy*WW + gx, o = ly*76 + lx;
        cu[o] = cb[g];
        vl[o] = vb[g];
        hl[o] = hb[g];
    }
    __syncthreads();

    #pragma unroll
    for (int k = 1; k <= 5; ++k){
        const int S = 74 - 2*k;
        const int trips = (S*S + 255) / 256;
        float val[21];
        #pragma unroll
        for (int i = 0; i < trips; ++i){
            int px = tid + i*256;
            if (px < S*S){
                int y = px / S + k, x = px % S + k;
                int o = y*76 + x;
                float c  = cu[o];
                float tp = cu[o - 76] * vl[o - 76];
                float bt = cu[o + 76] * vl[o];
                float lf = cu[o - 1]  * hl[o - 1];
                float rg = cu[o + 1]  * hl[o];
                val[i] = fmaxf(fmaxf(c, fmaxf(tp, bt)), fmaxf(lf, rg));
            }
        }
        __syncthreads();
        #pragma unroll
        for (int i = 0; i < trips; ++i){
            int px = tid + i*256;
            if (px < S*S){
                int y = px / S + k, x = px % S + k;
                cu[y*76 + x] = val[i];
            }
        }
        __syncthreads();
    }

    const int gyc = ty*64, gxc = tx*64;
    for (int i = tid; i < 64*64; i += 256){
        int y = i >> 6, x = i & 63;
        float v = cu[(y + 5)*76 + (x + 5)];
        int g = b*IMG + (gyc + y)*WW + (gxc + x);
        if (FINAL) dout[g] = fminf(mask[g], 1.f - v);
        else       cout[g] = v;
    }
}

extern "C" void kernel_launch(void* const* d_in, const int* in_sizes, int n_in,
                              void* d_out, int out_size, void* d_ws, size_t ws_size,
                              hipStream_t stream)
{
    const float* img  = (const float*)d_in[0];
    // d_in[1] (pred_img) unused by the reference.
    const float* mask = (const float*)d_in[2];
    const float* w1   = (const float*)d_in[3];
    const float* b1   = (const float*)d_in[4];
    const float* w2   = (const float*)d_in[5];
    const float* b2   = (const float*)d_in[6];
    float* out = (float*)d_out;

    float* vs   = (float*)d_ws;            // [8][512][512]
    float* hsm  = vs   + NB*IMG;
    float* curA = hsm  + NB*IMG;
    float* curB = curA + NB*IMG;
    uint4* wbuf = (uint4*)(curB + NB*IMG); // [4608] conv2 B-frags
    uint4* wabuf = wbuf + 4608;            // [256]  conv1 A-frags

    prep_kernel<<<37, 256, 0, stream>>>(w2, w1, wbuf, wabuf);
    erode_init_kernel<<<NB*IMG/256, 256, 0, stream>>>(mask, curA);
    conv_sims_kernel<<<NB*NTL*NTL, 256, 0, stream>>>(img, b1, wabuf, wbuf, b2, vs, hsm);

    prop5_kernel<false><<<512, 256, 0, stream>>>(curA, curB, vs, hsm, mask, out);
    prop5_kernel<true ><<<512, 256, 0, stream>>>(curB, curB, vs, hsm, mask, out);
}

// Round 5
// 444.374 us; speedup vs baseline: 7.8522x; 1.0280x over previous
//
#include <hip/hip_runtime.h>
#include <hip/hip_bf16.h>

#define HH 512
#define WW 512
#define NB 8
#define IMG (HH*WW)
#define TS 15
#define NTL 35   // ceil(511/15)+1 tiles cover rows 0..524

typedef __bf16 bf16x8 __attribute__((ext_vector_type(8)));
typedef float  f32x4  __attribute__((ext_vector_type(4)));

// ---------- bf16 helpers (RNE pack/unpack) ----------
__device__ __forceinline__ float bflo(unsigned u){ return __uint_as_float(u << 16); }
__device__ __forceinline__ float bfhi(unsigned u){ return __uint_as_float(u & 0xffff0000u); }
__device__ __forceinline__ unsigned f2bf_bits(float f){
    union { float f; unsigned u; } v; v.f = f;
    return (v.u + 0x7fffu + ((v.u >> 16) & 1u)) >> 16;   // RNE, finite inputs only
}
__device__ __forceinline__ unsigned packbf(float lo, float hi){
    return f2bf_bits(lo) | (f2bf_bits(hi) << 16);
}

// ---------- weight prep ----------
// wb: w2 [oc][ic][tap] -> frag [tap][ks][f][lane]: ic = ks*32+(l>>4)*8+j, oc = f*16+(l&15)
//     (used as conv2's A operand: row=oc, k=ic)
// wa: w1 [oc][k=27]    -> A-frag [mf][lane]:       oc = mf*16+(l&15), k = (l>>4)*8+j (k>=27 -> 0)
__global__ void prep_kernel(const float* __restrict__ w2, const float* __restrict__ w1,
                            uint4* __restrict__ wb, uint4* __restrict__ wa)
{
    int i = blockIdx.x * 256 + threadIdx.x;
    if (i < 9*2*4*64){
        int tap = i >> 9;
        int rem = i & 511;
        int ks  = rem >> 8;
        int nf  = (rem >> 6) & 3;
        int l   = rem & 63;
        int oc  = nf*16 + (l & 15);
        int icb = ks*32 + (l >> 4)*8;
        float v[8];
        #pragma unroll
        for (int j = 0; j < 8; ++j)
            v[j] = w2[(oc*64 + icb + j)*9 + tap];
        uint4 q;
        q.x = packbf(v[0], v[1]); q.y = packbf(v[2], v[3]);
        q.z = packbf(v[4], v[5]); q.w = packbf(v[6], v[7]);
        wb[i] = q;
    } else if (i < 9*2*4*64 + 4*64){
        int idx = i - 9*2*4*64;
        int mf = idx >> 6, l = idx & 63;
        int oc = mf*16 + (l & 15);
        int kb = (l >> 4)*8;
        float v[8];
        #pragma unroll
        for (int j = 0; j < 8; ++j)
            v[j] = (kb + j < 27) ? w1[oc*27 + kb + j] : 0.f;
        uint4 q;
        q.x = packbf(v[0], v[1]); q.y = packbf(v[2], v[3]);
        q.z = packbf(v[4], v[5]); q.w = packbf(v[6], v[7]);
        wa[idx] = q;
    }
}

// ---------- fused normalize + conv1(MFMA) + conv2(MFMA) + similarity maps ----------
// Tile: 15x15 sims; conv2 out 16x16; F 18x18 (halo 1); x 20x20 (halo 2).
// LDS: xs 4.8K + fs4 41.5K + union{xi 21.5K, ft4 32.8K} = 79 KB -> 2 blocks/CU.
__global__ __launch_bounds__(256, 2)
void conv_sims_kernel(const float* __restrict__ img,
                      const float* __restrict__ b1,
                      const uint4* __restrict__ wa,
                      const uint4* __restrict__ wb, const float* __restrict__ b2,
                      float* __restrict__ vs, float* __restrict__ hs)
{
    __shared__ float xs[3][20][20];
    __shared__ uint4 fs4[324*8];
    __shared__ uint4 uni[2048];          // xi (conv1 B operand) then ft4 (conv2 out)

    const int tid = threadIdx.x;
    const int bid = blockIdx.x;
    const int b   = bid / (NTL*NTL);
    const int t2  = bid % (NTL*NTL);
    const int th  = t2 / NTL, tw = t2 % NTL;
    const int h0  = th * TS, w0 = tw * TS;

    // ---- phase 1: stage normalized input (zero outside image) ----
    for (int i = tid; i < 3*20*20; i += 256){
        int ic = i / 400, r = (i / 20) % 20, c = i % 20;
        int gy = h0 - 2 + r, gx = w0 - 2 + c;
        float mean = (ic == 0) ? 0.485f : (ic == 1) ? 0.456f : 0.406f;
        float istd = (ic == 0) ? (1.f/0.229f) : (ic == 1) ? (1.f/0.224f) : (1.f/0.225f);
        float v = 0.f;
        if (gy >= 0 && gy < HH && gx >= 0 && gx < WW)
            v = (img[(b*3 + ic)*IMG + gy*WW + gx] - mean) * istd;
        xs[ic][r][c] = v;
    }
    __syncthreads();

    // ---- phase 2a: build im2col records xi[336][32 bf16], chunk-swizzled slot = c^(p&3) ----
    {
        uint4* xi = uni;
        for (int p = tid; p < 336; p += 256){
            uint4 c0 = {0,0,0,0}, c1 = c0, c2 = c0, c3 = c0;
            if (p < 324){
                int fy = p / 18, fx = p % 18;
                float xv[27];
                #pragma unroll
                for (int ic = 0; ic < 3; ++ic)
                    #pragma unroll
                    for (int ky = 0; ky < 3; ++ky)
                        #pragma unroll
                        for (int kx = 0; kx < 3; ++kx)
                            xv[ic*9 + ky*3 + kx] = xs[ic][fy + ky][fx + kx];
                c0.x = packbf(xv[0], xv[1]);  c0.y = packbf(xv[2], xv[3]);
                c0.z = packbf(xv[4], xv[5]);  c0.w = packbf(xv[6], xv[7]);
                c1.x = packbf(xv[8], xv[9]);  c1.y = packbf(xv[10], xv[11]);
                c1.z = packbf(xv[12], xv[13]);c1.w = packbf(xv[14], xv[15]);
                c2.x = packbf(xv[16], xv[17]);c2.y = packbf(xv[18], xv[19]);
                c2.z = packbf(xv[20], xv[21]);c2.w = packbf(xv[22], xv[23]);
                c3.x = packbf(xv[24], xv[25]);c3.y = packbf(xv[26], 0.f);
            }
            int sw = p & 3;
            xi[p*4 + (0 ^ sw)] = c0;
            xi[p*4 + (1 ^ sw)] = c1;
            xi[p*4 + (2 ^ sw)] = c2;
            xi[p*4 + (3 ^ sw)] = c3;
        }
    }
    __syncthreads();

    // ---- phase 2b: conv1 via MFMA. D[row=oc][col=pixel]; K=32 in one step. ----
    {
        const int l  = tid & 63, wv = tid >> 6;
        const int lr = l & 15,  kg = l >> 4;
        const bf16x8* wav = (const bf16x8*)wa;
        const bf16x8* xib = (const bf16x8*)uni;

        bf16x8 af[4];
        #pragma unroll
        for (int mf = 0; mf < 4; ++mf) af[mf] = wav[(mf << 6) + l];
        f32x4 binit[4];
        #pragma unroll
        for (int mf = 0; mf < 4; ++mf)
            binit[mf] = *(const f32x4*)(b1 + mf*16 + kg*4);

        for (int nb = wv; nb < 21; nb += 4){
            int px = nb*16 + lr;
            bf16x8 bf = xib[px*4 + (kg ^ (px & 3))];
            int fy = px / 18, fx = px % 18;
            int gy = h0 - 1 + fy, gx = w0 - 1 + fx;
            bool inimg = (px < 324) && gy >= 0 && gy < HH && gx >= 0 && gx < WW;
            #pragma unroll
            for (int mf = 0; mf < 4; ++mf){
                f32x4 acc = __builtin_amdgcn_mfma_f32_16x16x32_bf16(af[mf], bf, binit[mf], 0, 0, 0);
                unsigned lo = 0, hi = 0;
                if (inimg){
                    lo = packbf(fmaxf(acc[0], 0.f), fmaxf(acc[1], 0.f));
                    hi = packbf(fmaxf(acc[2], 0.f), fmaxf(acc[3], 0.f));
                }
                if (px < 324){
                    char* p8 = (char*)fs4 + px*128 + (((mf*2 + (kg >> 1)) ^ (px & 7)) << 4) + ((kg & 1) << 3);
                    uint2 w2v; w2v.x = lo; w2v.y = hi;
                    *(uint2*)p8 = w2v;
                }
            }
        }
    }
    __syncthreads();

    // ---- phase 3: conv2 (64->64) via MFMA. A=weights (row=oc), B=pixel records (col=px).
    //      D[row=oc][col=px] -> each lane holds 4 consecutive oc -> packed b64 ft writes. ----
    {
        const int wv = tid >> 6;
        const int l  = tid & 63;
        const int lr = l & 15;      // A row low (oc), B/D col (px)
        const int kg = l >> 4;

        // acc[mf][nf]: oc = mf*16 + kg*4 + r, px = wv*64 + nf*16 + lr
        f32x4 acc[4][4];
        #pragma unroll
        for (int mf = 0; mf < 4; ++mf){
            f32x4 bv = *(const f32x4*)(b2 + mf*16 + kg*4);
            #pragma unroll
            for (int nf = 0; nf < 4; ++nf) acc[mf][nf] = bv;
        }

        const bf16x8* fsb = (const bf16x8*)fs4;
        const bf16x8* wbv = (const bf16x8*)wb;

        #pragma unroll
        for (int tap = 0; tap < 9; ++tap){
            const int dy = tap / 3, dx = tap % 3;
            #pragma unroll
            for (int ks = 0; ks < 2; ++ks){
                bf16x8 wfr[4];
                #pragma unroll
                for (int mf = 0; mf < 4; ++mf)
                    wfr[mf] = wbv[((tap*8 + ks*4 + mf) << 6) + l];
                #pragma unroll
                for (int nf = 0; nf < 4; ++nf){
                    int fpx = (wv*4 + nf + dy)*18 + lr + dx;
                    bf16x8 bfr = fsb[fpx*8 + ((ks*4 + kg) ^ (fpx & 7))];
                    #pragma unroll
                    for (int mf = 0; mf < 4; ++mf)
                        acc[mf][nf] = __builtin_amdgcn_mfma_f32_16x16x32_bf16(
                            wfr[mf], bfr, acc[mf][nf], 0, 0, 0);
                }
            }
        }

        // write ft (relu, bf16, swizzled) with packed b64 stores
        char* ftb = (char*)uni;
        #pragma unroll
        for (int nf = 0; nf < 4; ++nf){
            int px = wv*64 + nf*16 + lr;
            char* pbase = ftb + px*128 + ((kg & 1) << 3);
            int swz = px & 7;
            #pragma unroll
            for (int mf = 0; mf < 4; ++mf){
                uint2 wv2;
                wv2.x = packbf(fmaxf(acc[mf][nf][0], 0.f), fmaxf(acc[mf][nf][1], 0.f));
                wv2.y = packbf(fmaxf(acc[mf][nf][2], 0.f), fmaxf(acc[mf][nf][3], 0.f));
                *(uint2*)(pbase + (((mf*2 + (kg >> 1)) ^ swz) << 4)) = wv2;
            }
        }
    }
    __syncthreads();

    // ---- phase 4: similarity maps (full coverage incl. zero row/col 511) ----
    const uint4* ft4 = uni;
    for (int s = tid; s < 450; s += 256){
        bool isv = (s < 225);
        int r  = isv ? s : (s - 225);
        int sy = r / 15, sx = r % 15;
        int gh = h0 + sy, gw = w0 + sx;
        if (gh >= HH || gw >= WW) continue;
        int pa = sy*16 + sx;
        int pb = isv ? (pa + 16) : (pa + 1);
        const uint4* A = ft4 + pa*8; int sa = pa & 7;
        const uint4* B = ft4 + pb*8; int sb = pb & 7;
        float ssd = 0.f;
        #pragma unroll
        for (int j = 0; j < 8; ++j){
            uint4 qa = A[j ^ sa], qb = B[j ^ sb];
            unsigned da[4] = {qa.x, qa.y, qa.z, qa.w};
            unsigned db[4] = {qb.x, qb.y, qb.z, qb.w};
            #pragma unroll
            for (int k = 0; k < 4; ++k){
                float d0 = bflo(da[k]) - bflo(db[k]);
                float d1 = bfhi(da[k]) - bfhi(db[k]);
                ssd = fmaf(d0, d0, ssd);
                ssd = fmaf(d1, d1, ssd);
            }
        }
        float sim = __expf(ssd * (-1.f/500.f));
        int o = b*IMG + gh*WW + gw;
        if (isv) vs[o] = (gh < HH-1) ? sim : 0.f;
        else     hs[o] = (gw < WW-1) ? sim : 0.f;
    }
}

// ---------- fused (erode +) 5-iteration Jacobi propagation ----------
// 64x64 tile + halo 5 in LDS. cu: stride 78, cur-space origin (1,1); FIRST also uses
// it as mask stage (halo 6, zero-padded, true coords) and computes erode in-place.
// Clamped staging reproduces the reference's clamped indexing exactly (round-1/4
// verified: pad terms are cur*sim <= cur, dominated under max).
template<bool FIRST, bool FINAL>
__global__ __launch_bounds__(256, 2)
void prop5_kernel(const float* __restrict__ cin, float* __restrict__ cout,
                  const float* __restrict__ vs, const float* __restrict__ hs,
                  const float* __restrict__ mask, float* __restrict__ dout)
{
    __shared__ float cu[76*78];
    __shared__ float vl[74*76];
    __shared__ float hl[74*76];

    const int tid = threadIdx.x;
    const int bid = blockIdx.x;                 // 512 = b(8) x ty(8) x tx(8)
    const int b  = bid >> 6;
    const int ty = (bid >> 3) & 7, tx = bid & 7;
    const int gy0 = ty*64 - 5, gx0 = tx*64 - 5;
    const float* vb = vs + b*IMG;
    const float* hb = hs + b*IMG;

    for (int i = tid; i < 74*74; i += 256){
        int ly = i / 74, lx = i % 74;
        int gy = min(max(gy0 + ly, 0), 511);
        int gx = min(max(gx0 + lx, 0), 511);
        int g = gy*WW + gx, o = ly*76 + lx;
        vl[o] = vb[g];
        hl[o] = hb[g];
    }

    if (FIRST){
        const float* mb = mask + b*IMG;
        // stage mask halo-6 (true coords, zero outside image)
        for (int i = tid; i < 76*76; i += 256){
            int ly = i / 76, lx = i % 76;
            int gy = gy0 - 1 + ly, gx = gx0 - 1 + lx;
            float v = 0.f;
            if (gy >= 0 && gy < HH && gx >= 0 && gx < WW) v = mb[gy*WW + gx];
            cu[ly*78 + lx] = v;
        }
        __syncthreads();
        // erode (zero-pad 3x3 sum > 1) -> cur0 = 1 - known, for in-image cells
        float val[22];
        #pragma unroll
        for (int i = 0; i < 22; ++i){
            int px = tid + i*256;
            if (px < 74*74){
                int ly = px / 74, lx = px % 74;
                int o = ly*78 + lx;
                float s = cu[o]     + cu[o+1]   + cu[o+2]
                        + cu[o+78]  + cu[o+79]  + cu[o+80]
                        + cu[o+156] + cu[o+157] + cu[o+158];
                val[i] = (s > 1.0f) ? 0.f : 1.f;
            }
        }
        __syncthreads();
        #pragma unroll
        for (int i = 0; i < 22; ++i){
            int px = tid + i*256;
            if (px < 74*74){
                int ly = px / 74, lx = px % 74;
                int gy = gy0 + ly, gx = gx0 + lx;
                if (gy >= 0 && gy < HH && gx >= 0 && gx < WW)
                    cu[(ly+1)*78 + (lx+1)] = val[i];
            }
        }
        __syncthreads();
        // fill out-of-image halo cells from their clamped in-image cells
        for (int i = tid; i < 74*74; i += 256){
            int ly = i / 74, lx = i % 74;
            int gy = gy0 + ly, gx = gx0 + lx;
            if (gy < 0 || gy >= HH || gx < 0 || gx >= WW){
                int cly = min(max(gy, 0), 511) - gy0;
                int clx = min(max(gx, 0), 511) - gx0;
                cu[(ly+1)*78 + (lx+1)] = cu[(cly+1)*78 + (clx+1)];
            }
        }
        __syncthreads();
    } else {
        const float* cb = cin + b*IMG;
        for (int i = tid; i < 74*74; i += 256){
            int ly = i / 74, lx = i % 74;
            int gy = min(max(gy0 + ly, 0), 511);
            int gx = min(max(gx0 + lx, 0), 511);
            cu[(ly+1)*78 + (lx+1)] = cb[gy*WW + gx];
        }
        __syncthreads();
    }

    #pragma unroll
    for (int k = 1; k <= 5; ++k){
        const int S = 74 - 2*k;
        const int trips = (S*S + 255) / 256;
        float val[21];
        #pragma unroll
        for (int i = 0; i < trips; ++i){
            int px = tid + i*256;
            if (px < S*S){
                int y = px / S + k, x = px % S + k;
                int oc_ = (y + 1)*78 + (x + 1);
                int os  = y*76 + x;
                float c  = cu[oc_];
                float tp = cu[oc_ - 78] * vl[os - 76];
                float bt = cu[oc_ + 78] * vl[os];
                float lf = cu[oc_ - 1]  * hl[os - 1];
                float rg = cu[oc_ + 1]  * hl[os];
                val[i] = fmaxf(fmaxf(c, fmaxf(tp, bt)), fmaxf(lf, rg));
            }
        }
        __syncthreads();
        #pragma unroll
        for (int i = 0; i < trips; ++i){
            int px = tid + i*256;
            if (px < S*S){
                int y = px / S + k, x = px % S + k;
                cu[(y + 1)*78 + (x + 1)] = val[i];
            }
        }
        __syncthreads();
    }

    const int gyc = ty*64, gxc = tx*64;
    for (int i = tid; i < 64*64; i += 256){
        int y = i >> 6, x = i & 63;
        float v = cu[(y + 6)*78 + (x + 6)];
        int g = b*IMG + (gyc + y)*WW + (gxc + x);
        if (FINAL) dout[g] = fminf(mask[g], 1.f - v);
        else       cout[g] = v;
    }
}

extern "C" void kernel_launch(void* const* d_in, const int* in_sizes, int n_in,
                              void* d_out, int out_size, void* d_ws, size_t ws_size,
                              hipStream_t stream)
{
    const float* img  = (const float*)d_in[0];
    // d_in[1] (pred_img) unused by the reference.
    const float* mask = (const float*)d_in[2];
    const float* w1   = (const float*)d_in[3];
    const float* b1   = (const float*)d_in[4];
    const float* w2   = (const float*)d_in[5];
    const float* b2   = (const float*)d_in[6];
    float* out = (float*)d_out;

    float* vs   = (float*)d_ws;            // [8][512][512]
    float* hsm  = vs   + NB*IMG;
    float* curB = hsm  + NB*IMG;
    uint4* wbuf = (uint4*)(curB + NB*IMG); // [4608] conv2 A-frags
    uint4* wabuf = wbuf + 4608;            // [256]  conv1 A-frags

    prep_kernel<<<37, 256, 0, stream>>>(w2, w1, wbuf, wabuf);
    conv_sims_kernel<<<NB*NTL*NTL, 256, 0, stream>>>(img, b1, wabuf, wbuf, b2, vs, hsm);

    prop5_kernel<true,  false><<<512, 256, 0, stream>>>(curB, curB, vs, hsm, mask, out);
    prop5_kernel<false, true ><<<512, 256, 0, stream>>>(curB, curB, vs, hsm, mask, out);
}

// Round 6
// 394.391 us; speedup vs baseline: 8.8474x; 1.1267x over previous
//
#include <hip/hip_runtime.h>
#include <hip/hip_bf16.h>

#define HH 512
#define WW 512
#define NB 8
#define IMG (HH*WW)
#define TS 15
#define NTL 35   // ceil(511/15)+1 tiles cover rows 0..524

typedef __bf16 bf16x8 __attribute__((ext_vector_type(8)));
typedef float  f32x4  __attribute__((ext_vector_type(4)));

// ---------- bf16 helpers ----------
__device__ __forceinline__ float bflo(unsigned u){ return __uint_as_float(u << 16); }
__device__ __forceinline__ float bfhi(unsigned u){ return __uint_as_float(u & 0xffff0000u); }
__device__ __forceinline__ unsigned f2bf_bits(float f){
    union { float f; unsigned u; } v; v.f = f;
    return (v.u + 0x7fffu + ((v.u >> 16) & 1u)) >> 16;   // RNE, finite inputs only
}
__device__ __forceinline__ unsigned packbf(float lo, float hi){
    return f2bf_bits(lo) | (f2bf_bits(hi) << 16);
}
// single-instruction packed f32->bf16 (RNE) — no builtin on gfx950, inline asm per T12
__device__ __forceinline__ unsigned cvtpk(float lo, float hi){
    unsigned r;
    asm("v_cvt_pk_bf16_f32 %0, %1, %2" : "=v"(r) : "v"(lo), "v"(hi));
    return r;
}

// ---------- weight prep ----------
// wb: w2 [oc][ic][tap] -> frag [tap][ks][f][lane]: ic = ks*32+(l>>4)*8+j, oc = f*16+(l&15)
//     (conv2 A operand: row=oc, k=ic)
// wa: w1 [oc][k=27]    -> A-frag [mf][lane]:       oc = mf*16+(l&15), k = (l>>4)*8+j (k>=27 -> 0)
__global__ void prep_kernel(const float* __restrict__ w2, const float* __restrict__ w1,
                            uint4* __restrict__ wb, uint4* __restrict__ wa)
{
    int i = blockIdx.x * 256 + threadIdx.x;
    if (i < 9*2*4*64){
        int tap = i >> 9;
        int rem = i & 511;
        int ks  = rem >> 8;
        int nf  = (rem >> 6) & 3;
        int l   = rem & 63;
        int oc  = nf*16 + (l & 15);
        int icb = ks*32 + (l >> 4)*8;
        float v[8];
        #pragma unroll
        for (int j = 0; j < 8; ++j)
            v[j] = w2[(oc*64 + icb + j)*9 + tap];
        uint4 q;
        q.x = packbf(v[0], v[1]); q.y = packbf(v[2], v[3]);
        q.z = packbf(v[4], v[5]); q.w = packbf(v[6], v[7]);
        wb[i] = q;
    } else if (i < 9*2*4*64 + 4*64){
        int idx = i - 9*2*4*64;
        int mf = idx >> 6, l = idx & 63;
        int oc = mf*16 + (l & 15);
        int kb = (l >> 4)*8;
        float v[8];
        #pragma unroll
        for (int j = 0; j < 8; ++j)
            v[j] = (kb + j < 27) ? w1[oc*27 + kb + j] : 0.f;
        uint4 q;
        q.x = packbf(v[0], v[1]); q.y = packbf(v[2], v[3]);
        q.z = packbf(v[4], v[5]); q.w = packbf(v[6], v[7]);
        wa[idx] = q;
    }
}

// ---------- fused normalize + conv1(MFMA) + conv2(MFMA) + similarity maps ----------
// Tile: 15x15 sims; conv2 out 16x16; F 18x18 (halo 1); x 20x20 (halo 2).
// All LDS tensors chunk-major SoA [chunk][pixel] -> 16 lanes x 16B consecutive,
// conflict-free with zero swizzle math.
// LDS: xs 4.8K + fs 41.5K + union{xi 21.5K, ft 32.8K} = 79 KB -> 2 blocks/CU.
__global__ __launch_bounds__(256, 2)
void conv_sims_kernel(const float* __restrict__ img,
                      const float* __restrict__ b1,
                      const uint4* __restrict__ wa,
                      const uint4* __restrict__ wb, const float* __restrict__ b2,
                      float* __restrict__ vs, float* __restrict__ hs)
{
    __shared__ float xs[3][20][20];
    __shared__ uint4 fs4[8*324];         // fs4[c*324 + px], c = ic_chunk 0..7
    __shared__ uint4 uni[2048];          // xi[c*336+px] (c 0..3) then ft[c*256+px] (c 0..7)

    const int tid = threadIdx.x;
    const int bid = blockIdx.x;
    const int b   = bid / (NTL*NTL);
    const int t2  = bid % (NTL*NTL);
    const int th  = t2 / NTL, tw = t2 % NTL;
    const int h0  = th * TS, w0 = tw * TS;

    // ---- phase 1: stage normalized input (zero outside image) ----
    for (int i = tid; i < 3*20*20; i += 256){
        int ic = i / 400, r = (i / 20) % 20, c = i % 20;
        int gy = h0 - 2 + r, gx = w0 - 2 + c;
        float mean = (ic == 0) ? 0.485f : (ic == 1) ? 0.456f : 0.406f;
        float istd = (ic == 0) ? (1.f/0.229f) : (ic == 1) ? (1.f/0.224f) : (1.f/0.225f);
        float v = 0.f;
        if (gy >= 0 && gy < HH && gx >= 0 && gx < WW)
            v = (img[(b*3 + ic)*IMG + gy*WW + gx] - mean) * istd;
        xs[ic][r][c] = v;
    }
    __syncthreads();

    // ---- phase 2a: im2col records xi[4][336] chunk-major ----
    {
        for (int p = tid; p < 336; p += 256){
            uint4 c0 = {0,0,0,0}, c1 = c0, c2 = c0, c3 = c0;
            if (p < 324){
                int fy = p / 18, fx = p % 18;
                float xv[27];
                #pragma unroll
                for (int ic = 0; ic < 3; ++ic)
                    #pragma unroll
                    for (int ky = 0; ky < 3; ++ky)
                        #pragma unroll
                        for (int kx = 0; kx < 3; ++kx)
                            xv[ic*9 + ky*3 + kx] = xs[ic][fy + ky][fx + kx];
                c0.x = cvtpk(xv[0], xv[1]);  c0.y = cvtpk(xv[2], xv[3]);
                c0.z = cvtpk(xv[4], xv[5]);  c0.w = cvtpk(xv[6], xv[7]);
                c1.x = cvtpk(xv[8], xv[9]);  c1.y = cvtpk(xv[10], xv[11]);
                c1.z = cvtpk(xv[12], xv[13]);c1.w = cvtpk(xv[14], xv[15]);
                c2.x = cvtpk(xv[16], xv[17]);c2.y = cvtpk(xv[18], xv[19]);
                c2.z = cvtpk(xv[20], xv[21]);c2.w = cvtpk(xv[22], xv[23]);
                c3.x = cvtpk(xv[24], xv[25]);c3.y = cvtpk(xv[26], 0.f);
            }
            uni[0*336 + p] = c0;
            uni[1*336 + p] = c1;
            uni[2*336 + p] = c2;
            uni[3*336 + p] = c3;
        }
    }
    __syncthreads();

    // ---- phase 2b: conv1 via MFMA. D[row=oc][col=pixel]; K=32 in one step. ----
    {
        const int l  = tid & 63, wv = tid >> 6;
        const int lr = l & 15,  kg = l >> 4;
        const bf16x8* wav = (const bf16x8*)wa;
        const bf16x8* xib = (const bf16x8*)uni;

        bf16x8 af[4];
        #pragma unroll
        for (int mf = 0; mf < 4; ++mf) af[mf] = wav[(mf << 6) + l];
        f32x4 binit[4];
        #pragma unroll
        for (int mf = 0; mf < 4; ++mf)
            binit[mf] = *(const f32x4*)(b1 + mf*16 + kg*4);

        for (int nb = wv; nb < 21; nb += 4){
            int px = nb*16 + lr;
            bf16x8 bf = xib[kg*336 + px];
            int fy = px / 18, fx = px % 18;
            int gy = h0 - 1 + fy, gx = w0 - 1 + fx;
            bool inimg = (px < 324) && gy >= 0 && gy < HH && gx >= 0 && gx < WW;
            #pragma unroll
            for (int mf = 0; mf < 4; ++mf){
                f32x4 acc = __builtin_amdgcn_mfma_f32_16x16x32_bf16(af[mf], bf, binit[mf], 0, 0, 0);
                unsigned lo = 0, hi = 0;
                if (inimg){
                    lo = cvtpk(fmaxf(acc[0], 0.f), fmaxf(acc[1], 0.f));
                    hi = cvtpk(fmaxf(acc[2], 0.f), fmaxf(acc[3], 0.f));
                }
                if (px < 324){
                    // value oc = mf*16 + kg*4 + r -> chunk = mf*2 + (kg>>1), 8B half = kg&1
                    char* p8 = (char*)fs4 + (((mf*2 + (kg >> 1)) * 324 + px) << 4) + ((kg & 1) << 3);
                    uint2 w2v; w2v.x = lo; w2v.y = hi;
                    *(uint2*)p8 = w2v;
                }
            }
        }
    }
    __syncthreads();

    // ---- phase 3: conv2 (64->64) via MFMA. A=weights (row=oc), B=pixel records (col=px). ----
    {
        const int wv = tid >> 6;
        const int l  = tid & 63;
        const int lr = l & 15;      // B/D col (px)
        const int kg = l >> 4;

        // acc[mf][nf]: oc = mf*16 + kg*4 + r, px = wv*64 + nf*16 + lr
        f32x4 acc[4][4];
        #pragma unroll
        for (int mf = 0; mf < 4; ++mf){
            f32x4 bv = *(const f32x4*)(b2 + mf*16 + kg*4);
            #pragma unroll
            for (int nf = 0; nf < 4; ++nf) acc[mf][nf] = bv;
        }

        const bf16x8* fsb = (const bf16x8*)fs4;
        const bf16x8* wbv = (const bf16x8*)wb;

        #pragma unroll
        for (int tap = 0; tap < 9; ++tap){
            const int dy = tap / 3, dx = tap % 3;
            #pragma unroll
            for (int ks = 0; ks < 2; ++ks){
                bf16x8 wfr[4];
                #pragma unroll
                for (int mf = 0; mf < 4; ++mf)
                    wfr[mf] = wbv[((tap*8 + ks*4 + mf) << 6) + l];
                #pragma unroll
                for (int nf = 0; nf < 4; ++nf){
                    int fpx = (wv*4 + nf + dy)*18 + lr + dx;
                    bf16x8 bfr = fsb[(ks*4 + kg)*324 + fpx];
                    #pragma unroll
                    for (int mf = 0; mf < 4; ++mf)
                        acc[mf][nf] = __builtin_amdgcn_mfma_f32_16x16x32_bf16(
                            wfr[mf], bfr, acc[mf][nf], 0, 0, 0);
                }
            }
        }

        // write ft (relu, bf16, chunk-major) with packed b64 stores
        char* ftb = (char*)uni;
        #pragma unroll
        for (int nf = 0; nf < 4; ++nf){
            int px = wv*64 + nf*16 + lr;
            #pragma unroll
            for (int mf = 0; mf < 4; ++mf){
                uint2 wv2;
                wv2.x = cvtpk(fmaxf(acc[mf][nf][0], 0.f), fmaxf(acc[mf][nf][1], 0.f));
                wv2.y = cvtpk(fmaxf(acc[mf][nf][2], 0.f), fmaxf(acc[mf][nf][3], 0.f));
                *(uint2*)(ftb + (((mf*2 + (kg >> 1)) * 256 + px) << 4) + ((kg & 1) << 3)) = wv2;
            }
        }
    }
    __syncthreads();

    // ---- phase 4: similarity maps (full coverage incl. zero row/col 511) ----
    const uint4* ft4 = uni;
    for (int s = tid; s < 450; s += 256){
        bool isv = (s < 225);
        int r  = isv ? s : (s - 225);
        int sy = r / 15, sx = r % 15;
        int gh = h0 + sy, gw = w0 + sx;
        if (gh >= HH || gw >= WW) continue;
        int pa = sy*16 + sx;
        int pb = isv ? (pa + 16) : (pa + 1);
        float ssd = 0.f;
        #pragma unroll
        for (int j = 0; j < 8; ++j){
            uint4 qa = ft4[j*256 + pa], qb = ft4[j*256 + pb];
            unsigned da[4] = {qa.x, qa.y, qa.z, qa.w};
            unsigned db[4] = {qb.x, qb.y, qb.z, qb.w};
            #pragma unroll
            for (int k = 0; k < 4; ++k){
                float d0 = bflo(da[k]) - bflo(db[k]);
                float d1 = bfhi(da[k]) - bfhi(db[k]);
                ssd = fmaf(d0, d0, ssd);
                ssd = fmaf(d1, d1, ssd);
            }
        }
        float sim = __expf(ssd * (-1.f/500.f));
        int o = b*IMG + gh*WW + gw;
        if (isv) vs[o] = (gh < HH-1) ? sim : 0.f;
        else     hs[o] = (gw < WW-1) ? sim : 0.f;
    }
}

// ---------- fused (erode +) 5-iteration Jacobi propagation ----------
// 64x64 tile + halo 5 in LDS. cu: stride 78, cur-space origin (1,1); FIRST also uses
// it as mask stage (halo 6, zero-padded, true coords) and computes erode in-place.
// Clamped staging reproduces the reference's clamped indexing exactly (pad terms
// are cur*sim <= cur, dominated under max; verified rounds 1-5).
template<bool FIRST, bool FINAL>
__global__ __launch_bounds__(256, 2)
void prop5_kernel(const float* __restrict__ cin, float* __restrict__ cout,
                  const float* __restrict__ vs, const float* __restrict__ hs,
                  const float* __restrict__ mask, float* __restrict__ dout)
{
    __shared__ float cu[76*78];
    __shared__ float vl[74*76];
    __shared__ float hl[74*76];

    const int tid = threadIdx.x;
    const int bid = blockIdx.x;                 // 512 = b(8) x ty(8) x tx(8)
    const int b  = bid >> 6;
    const int ty = (bid >> 3) & 7, tx = bid & 7;
    const int gy0 = ty*64 - 5, gx0 = tx*64 - 5;
    const float* vb = vs + b*IMG;
    const float* hb = hs + b*IMG;

    for (int i = tid; i < 74*74; i += 256){
        int ly = i / 74, lx = i % 74;
        int gy = min(max(gy0 + ly, 0), 511);
        int gx = min(max(gx0 + lx, 0), 511);
        int g = gy*WW + gx, o = ly*76 + lx;
        vl[o] = vb[g];
        hl[o] = hb[g];
    }

    if (FIRST){
        const float* mb = mask + b*IMG;
        for (int i = tid; i < 76*76; i += 256){
            int ly = i / 76, lx = i % 76;
            int gy = gy0 - 1 + ly, gx = gx0 - 1 + lx;
            float v = 0.f;
            if (gy >= 0 && gy < HH && gx >= 0 && gx < WW) v = mb[gy*WW + gx];
            cu[ly*78 + lx] = v;
        }
        __syncthreads();
        float val[22];
        #pragma unroll
        for (int i = 0; i < 22; ++i){
            int px = tid + i*256;
            if (px < 74*74){
                int ly = px / 74, lx = px % 74;
                int o = ly*78 + lx;
                float s = cu[o]     + cu[o+1]   + cu[o+2]
                        + cu[o+78]  + cu[o+79]  + cu[o+80]
                        + cu[o+156] + cu[o+157] + cu[o+158];
                val[i] = (s > 1.0f) ? 0.f : 1.f;
            }
        }
        __syncthreads();
        #pragma unroll
        for (int i = 0; i < 22; ++i){
            int px = tid + i*256;
            if (px < 74*74){
                int ly = px / 74, lx = px % 74;
                int gy = gy0 + ly, gx = gx0 + lx;
                if (gy >= 0 && gy < HH && gx >= 0 && gx < WW)
                    cu[(ly+1)*78 + (lx+1)] = val[i];
            }
        }
        __syncthreads();
        for (int i = tid; i < 74*74; i += 256){
            int ly = i / 74, lx = i % 74;
            int gy = gy0 + ly, gx = gx0 + lx;
            if (gy < 0 || gy >= HH || gx < 0 || gx >= WW){
                int cly = min(max(gy, 0), 511) - gy0;
                int clx = min(max(gx, 0), 511) - gx0;
                cu[(ly+1)*78 + (lx+1)] = cu[(cly+1)*78 + (clx+1)];
            }
        }
        __syncthreads();
    } else {
        const float* cb = cin + b*IMG;
        for (int i = tid; i < 74*74; i += 256){
            int ly = i / 74, lx = i % 74;
            int gy = min(max(gy0 + ly, 0), 511);
            int gx = min(max(gx0 + lx, 0), 511);
            cu[(ly+1)*78 + (lx+1)] = cb[gy*WW + gx];
        }
        __syncthreads();
    }

    #pragma unroll
    for (int k = 1; k <= 5; ++k){
        const int S = 74 - 2*k;
        const int trips = (S*S + 255) / 256;
        float val[21];
        #pragma unroll
        for (int i = 0; i < trips; ++i){
            int px = tid + i*256;
            if (px < S*S){
                int y = px / S + k, x = px % S + k;
                int oc_ = (y + 1)*78 + (x + 1);
                int os  = y*76 + x;
                float c  = cu[oc_];
                float tp = cu[oc_ - 78] * vl[os - 76];
                float bt = cu[oc_ + 78] * vl[os];
                float lf = cu[oc_ - 1]  * hl[os - 1];
                float rg = cu[oc_ + 1]  * hl[os];
                val[i] = fmaxf(fmaxf(c, fmaxf(tp, bt)), fmaxf(lf, rg));
            }
        }
        __syncthreads();
        #pragma unroll
        for (int i = 0; i < trips; ++i){
            int px = tid + i*256;
            if (px < S*S){
                int y = px / S + k, x = px % S + k;
                cu[(y + 1)*78 + (x + 1)] = val[i];
            }
        }
        __syncthreads();
    }

    const int gyc = ty*64, gxc = tx*64;
    for (int i = tid; i < 64*64; i += 256){
        int y = i >> 6, x = i & 63;
        float v = cu[(y + 6)*78 + (x + 6)];
        int g = b*IMG + (gyc + y)*WW + (gxc + x);
        if (FINAL) dout[g] = fminf(mask[g], 1.f - v);
        else       cout[g] = v;
    }
}

extern "C" void kernel_launch(void* const* d_in, const int* in_sizes, int n_in,
                              void* d_out, int out_size, void* d_ws, size_t ws_size,
                              hipStream_t stream)
{
    const float* img  = (const float*)d_in[0];
    // d_in[1] (pred_img) unused by the reference.
    const float* mask = (const float*)d_in[2];
    const float* w1   = (const float*)d_in[3];
    const float* b1   = (const float*)d_in[4];
    const float* w2   = (const float*)d_in[5];
    const float* b2   = (const float*)d_in[6];
    float* out = (float*)d_out;

    float* vs   = (float*)d_ws;            // [8][512][512]
    float* hsm  = vs   + NB*IMG;
    float* curB = hsm  + NB*IMG;
    uint4* wbuf = (uint4*)(curB + NB*IMG); // [4608] conv2 A-frags
    uint4* wabuf = wbuf + 4608;            // [256]  conv1 A-frags

    prep_kernel<<<37, 256, 0, stream>>>(w2, w1, wbuf, wabuf);
    conv_sims_kernel<<<NB*NTL*NTL, 256, 0, stream>>>(img, b1, wabuf, wbuf, b2, vs, hsm);

    prop5_kernel<true,  false><<<512, 256, 0, stream>>>(curB, curB, vs, hsm, mask, out);
    prop5_kernel<false, true ><<<512, 256, 0, stream>>>(curB, curB, vs, hsm, mask, out);
}